// Round 1
// baseline (9.727 us; speedup 1.0000x reference)
//
#include <hip/hip_runtime.h>
#include <cstdint>
#include <cstddef>

// microGIF single step, N = 8192.
//
// Reference math:
//   theta_next = theta_v + (THETA_INF - theta_v + J_theta*spiked_prev)/tau_theta
//   t   = time_since_spike - 3.0
//   eps = (0.5 + 0.5*tanh(t)) * exp(-t/tau_s) / tau_s
//   x   = eps * pop_sizes * spiked_prev                (row vector, length N)
//   I_syn[j] = tau_m[j] * ( sum_{i != j} x[i]*sign[i]*w[i][j] ) / R_m[j]
//   v_next = v + (E_L - v + R_m*(I_syn + I_ext))/tau_m
//   lambda = c * exp((v_next - theta_next)/5)
//   spiked = (noise < clip(lambda,0,1)) ? 1 : 0
//
// Key optimization: x is gated by spiked_prev. Rows with spiked_prev[i]==0
// contribute nothing, so we build x in LDS and only read w's rows where
// x is nonzero (zero rows -> the 256 MB w matrix is never touched).
// Deterministic: same inputs -> same branch decisions -> same output.

#define NN 8192
#define BLOCK 256

__global__ __launch_bounds__(BLOCK) void microgif_step(
    const float* __restrict__ I_ext,        // in[0]
    const float* __restrict__ noise,        // in[1]
    const float* __restrict__ w,            // in[2]  (N x N)
    const float* __restrict__ E_L,          // in[3]
    const float* __restrict__ tau_m,        // in[4]
    const float* __restrict__ tau_s,        // in[5]
    const float* __restrict__ tau_theta,    // in[6]
    const float* __restrict__ J_theta,      // in[7]
    const float* __restrict__ v,            // in[8]
    const float* __restrict__ spiked_prev,  // in[9]
    const float* __restrict__ tss,          // in[10] time_since_spike
    const float* __restrict__ theta_v,      // in[11]
    const float* __restrict__ R_m,          // in[12]
    const float* __restrict__ c,            // in[13]
    const float* __restrict__ pop_sizes,    // in[14]
    const float* __restrict__ neuron_sign,  // in[15]
    float* __restrict__ out)                // out[0..N)=lambda, out[N..2N)=spiked
{
    __shared__ float s_x[NN];   // x[i] * sign[i], dense (32 KB)
    __shared__ int   s_nnz;     // count of float4-chunks containing a nonzero

    const int tid = threadIdx.x;
    if (tid == 0) s_nnz = 0;
    __syncthreads();

    // ---- Phase 1: every block scans spiked_prev, builds signed x in LDS ----
    for (int base = tid * 4; base < NN; base += BLOCK * 4) {
        float4 sp = *reinterpret_cast<const float4*>(&spiked_prev[base]);
        float4 xv = make_float4(0.f, 0.f, 0.f, 0.f);
        bool any = false;
        #pragma unroll
        for (int e = 0; e < 4; ++e) {
            float spv = (&sp.x)[e];
            if (spv != 0.0f) {
                const int i = base + e;
                const float ts  = tss[i] - 3.0f;                 // Delta_delay + t_ref
                const float tsi = tau_s[i];
                const float eps = (0.5f + 0.5f * tanhf(ts)) * expf(-ts / tsi) / tsi;
                (&xv.x)[e] = eps * pop_sizes[i] * spv * neuron_sign[i];
                any = true;
            }
        }
        *reinterpret_cast<float4*>(&s_x[base]) = xv;
        if (any) atomicAdd(&s_nnz, 1);
    }
    __syncthreads();

    const int j = blockIdx.x * BLOCK + tid;   // output neuron (column of W)

    // ---- Phase 2: column accumulation over nonzero rows only ----
    float acc = 0.0f;
    if (s_nnz != 0) {
        for (int i = 0; i < NN; ++i) {
            const float xv = s_x[i];
            if (xv != 0.0f && i != j) {
                acc += xv * w[(size_t)i * NN + j];   // coalesced across j
            }
        }
    }

    // ---- Phase 3: per-neuron scalar update + outputs ----
    const float th         = theta_v[j];
    const float theta_next = th + (15.0f - th + J_theta[j] * spiked_prev[j]) / tau_theta[j];
    const float tm         = tau_m[j];
    const float rm         = R_m[j];
    const float I_syn      = tm * acc / rm;
    const float vj         = v[j];
    const float v_next     = vj + (E_L[j] - vj + rm * (I_syn + I_ext[j])) / tm;
    const float lam        = c[j] * expf((v_next - theta_next) / 5.0f);
    const float lam_clip   = fminf(fmaxf(lam, 0.0f), 1.0f);
    const float spiked     = (noise[j] < lam_clip) ? 1.0f : 0.0f;

    out[j]      = lam;
    out[NN + j] = spiked;
}

extern "C" void kernel_launch(void* const* d_in, const int* in_sizes, int n_in,
                              void* d_out, int out_size, void* d_ws, size_t ws_size,
                              hipStream_t stream) {
    (void)in_sizes; (void)n_in; (void)d_ws; (void)ws_size; (void)out_size;

    const float* I_ext       = (const float*)d_in[0];
    const float* noise       = (const float*)d_in[1];
    const float* w           = (const float*)d_in[2];
    const float* E_L         = (const float*)d_in[3];
    const float* tau_m       = (const float*)d_in[4];
    const float* tau_s       = (const float*)d_in[5];
    const float* tau_theta   = (const float*)d_in[6];
    const float* J_theta     = (const float*)d_in[7];
    const float* v           = (const float*)d_in[8];
    const float* spiked_prev = (const float*)d_in[9];
    const float* tss         = (const float*)d_in[10];
    const float* theta_v     = (const float*)d_in[11];
    const float* R_m         = (const float*)d_in[12];
    const float* c           = (const float*)d_in[13];
    const float* pop_sizes   = (const float*)d_in[14];
    const float* neuron_sign = (const float*)d_in[15];
    float* out               = (float*)d_out;

    microgif_step<<<NN / BLOCK, BLOCK, 0, stream>>>(
        I_ext, noise, w, E_L, tau_m, tau_s, tau_theta, J_theta,
        v, spiked_prev, tss, theta_v, R_m, c, pop_sizes, neuron_sign, out);
}